// Round 6
// baseline (183.701 us; speedup 1.0000x reference)
//
#include <hip/hip_runtime.h>
#include <stdint.h>
#include <stddef.h>

#define B_ 8
#define L_ 2048
#define D_ 256
#define KRANGE 512
#define KTILE 64
#define NITER 8

typedef __bf16 bf16x8 __attribute__((ext_vector_type(8)));
typedef float floatx4 __attribute__((ext_vector_type(4)));
typedef float floatx16 __attribute__((ext_vector_type(16)));
typedef _Float16 half4_t __attribute__((ext_vector_type(4)));

__device__ __forceinline__ short f2bf(float f) {   // round-half-up (cheap)
    union { float f; uint32_t u; } v; v.f = f;
    return (short)((v.u + 0x8000u) >> 16);
}

__device__ __forceinline__ uint32_t pack2bf(float a, float b) {
    union { float f; uint32_t u; } x, y; x.f = a; y.f = b;
    return ((x.u + 0x8000u) >> 16) | ((y.u + 0x8000u) & 0xFFFF0000u);
}

__device__ __forceinline__ uint32_t cvtpk_bf16(float lo, float hi2) {
    uint32_t w;
    asm("v_cvt_pk_bf16_f32 %0, %1, %2" : "=v"(w) : "v"(lo), "v"(hi2));
    return w;
}

// swap(a[l+32], b[l]) for l<32: a's upper lanes <-> b's lower lanes
__device__ __forceinline__ void pl32swap(uint32_t &a, uint32_t &b) {
    asm("v_permlane32_swap_b32 %0, %1" : "+v"(a), "+v"(b));
}

__device__ __forceinline__ void async16(const void* g, void* l) {
    __builtin_amdgcn_global_load_lds(
        (__attribute__((address_space(1))) void*)g,
        (__attribute__((address_space(3))) void*)l,
        16, 0, 0);
}

// ---------------------------------------------------------------------------
// Fused q/k projection, double-buffered LDS: Out = bf16(X @ W^T + bias).
// (separate from vtrans: merged version measured +10us — R4 post-mortem)
// ---------------------------------------------------------------------------
__global__ __launch_bounds__(256, 3) void proj_kernel(
    const float* __restrict__ Xq, const float* __restrict__ Xk,
    const float* __restrict__ Wq, const float* __restrict__ Wk,
    const float* __restrict__ bq, const float* __restrict__ bk,
    short* __restrict__ Oq, short* __restrict__ Ok)
{
    const float* X    = blockIdx.y ? Xk : Xq;
    const float* W    = blockIdx.y ? Wk : Wq;
    const float* bias = blockIdx.y ? bk : bq;
    short* Out        = blockIdx.y ? Ok : Oq;

    __shared__ uint32_t As[2][64 * 20];
    __shared__ uint32_t Ws[2][256 * 20];

    const int tid  = threadIdx.x;
    const int wid  = tid >> 6;
    const int lane = tid & 63;
    const int m16  = lane & 15;
    const int quad = lane >> 4;
    const int row0 = blockIdx.x * 64;
    const int ar = tid >> 2, cg = tid & 3;

    floatx4 acc[16];
    const floatx4 z4 = {0.f, 0.f, 0.f, 0.f};
#pragma unroll
    for (int i = 0; i < 16; i++) acc[i] = z4;

    // prologue: load + pack kc=0 into buf 0
    {
        const float* srcA = X + (size_t)(row0 + ar) * D_ + cg * 8;
        float4 a = *(const float4*)srcA, b2 = *(const float4*)(srcA + 4);
        uint4 u; u.x = pack2bf(a.x, a.y); u.y = pack2bf(a.z, a.w);
        u.z = pack2bf(b2.x, b2.y); u.w = pack2bf(b2.z, b2.w);
        *(uint4*)&As[0][ar * 20 + cg * 4] = u;
#pragma unroll
        for (int p = 0; p < 4; p++) {
            const float* srcW = W + (size_t)(p * 64 + ar) * D_ + cg * 8;
            float4 wa = *(const float4*)srcW, wb = *(const float4*)(srcW + 4);
            uint4 w; w.x = pack2bf(wa.x, wa.y); w.y = pack2bf(wa.z, wa.w);
            w.z = pack2bf(wb.x, wb.y); w.w = pack2bf(wb.z, wb.w);
            *(uint4*)&Ws[0][(p * 64 + ar) * 20 + cg * 4] = w;
        }
    }
    __syncthreads();

    for (int kc = 0; kc < 8; kc++) {
        const int buf = kc & 1;
        // issue global loads for kc+1
        float4 na, nb, nwa[4], nwb[4];
        if (kc < 7) {
            const int k1 = (kc + 1) * 32;
            const float* srcA = X + (size_t)(row0 + ar) * D_ + k1 + cg * 8;
            na = *(const float4*)srcA; nb = *(const float4*)(srcA + 4);
#pragma unroll
            for (int p = 0; p < 4; p++) {
                const float* srcW = W + (size_t)(p * 64 + ar) * D_ + k1 + cg * 8;
                nwa[p] = *(const float4*)srcW; nwb[p] = *(const float4*)(srcW + 4);
            }
        }
        // MFMA on current buffer
        bf16x8 af = *(const bf16x8*)&As[buf][(wid * 16 + m16) * 20 + quad * 4];
#pragma unroll
        for (int n = 0; n < 16; n++) {
            bf16x8 bfr = *(const bf16x8*)&Ws[buf][(n * 16 + m16) * 20 + quad * 4];
            acc[n] = __builtin_amdgcn_mfma_f32_16x16x32_bf16(af, bfr, acc[n], 0, 0, 0);
        }
        // pack + write next buffer
        if (kc < 7) {
            uint4 u; u.x = pack2bf(na.x, na.y); u.y = pack2bf(na.z, na.w);
            u.z = pack2bf(nb.x, nb.y); u.w = pack2bf(nb.z, nb.w);
            *(uint4*)&As[buf ^ 1][ar * 20 + cg * 4] = u;
#pragma unroll
            for (int p = 0; p < 4; p++) {
                uint4 w; w.x = pack2bf(nwa[p].x, nwa[p].y); w.y = pack2bf(nwa[p].z, nwa[p].w);
                w.z = pack2bf(nwb[p].x, nwb[p].y); w.w = pack2bf(nwb[p].z, nwb[p].w);
                *(uint4*)&Ws[buf ^ 1][(p * 64 + ar) * 20 + cg * 4] = w;
            }
        }
        __syncthreads();
    }
#pragma unroll
    for (int n = 0; n < 16; n++) {
        const int col = n * 16 + m16;
        const float bv = bias[col];
#pragma unroll
        for (int r = 0; r < 4; r++) {
            const int row = row0 + wid * 16 + quad * 4 + r;
            Out[(size_t)row * D_ + col] = f2bf(acc[n][r] + bv);
        }
    }
}

// ---------------------------------------------------------------------------
// V transpose: Vt[b][d][l] = bf16(V[b][l][d]).
// ---------------------------------------------------------------------------
__global__ __launch_bounds__(256, 2) void vtrans_kernel(
    const float* __restrict__ V, short* __restrict__ Vt)
{
    __shared__ uint32_t T[256 * 20];
    const int tid = threadIdx.x;
    const int b  = blockIdx.y;
    const int l0 = blockIdx.x * 32;
    const int r2 = tid >> 4;
    const int dg = tid & 15;
    const int lp = r2 ^ ((dg & 3) << 2);
#pragma unroll
    for (int p = 0; p < 4; p++) {
        int d0 = (dg + p * 16) * 4;
        const float* src = V + ((size_t)b * L_ + l0 + r2 * 2) * D_ + d0;
        float4 e0 = *(const float4*)src;
        float4 e1 = *(const float4*)(src + D_);
        T[(d0 + 0) * 20 + lp] = pack2bf(e0.x, e1.x);
        T[(d0 + 1) * 20 + lp] = pack2bf(e0.y, e1.y);
        T[(d0 + 2) * 20 + lp] = pack2bf(e0.z, e1.z);
        T[(d0 + 3) * 20 + lp] = pack2bf(e0.w, e1.w);
    }
    __syncthreads();
#pragma unroll
    for (int p = 0; p < 4; p++) {
        int d = (tid >> 2) + p * 64;
        int c = tid & 3;
        int cp = c ^ ((d >> 2) & 3);
        uint4 u = *(const uint4*)&T[d * 20 + cp * 4];
        *(uint4*)(Vt + ((size_t)b * D_ + d) * L_ + l0 + c * 8) = u;
    }
}

// ---------------------------------------------------------------------------
// Flash attention, static softmax, ksplit=4, 32x32x16 MFMA, swapped QK^T.
// KTILE=64 / NITER=8: per iter = QK0 -> PV_AB(t-1) -> sm0 -> QK1 ->
// PV_CD(t-1) -> sm1 -> barrier. Halves barrier/drain events vs KTILE=32 and
// interleaves independent PV MFMAs into the QK dependency chain; sm (VALU)
// overlaps the other wave's MFMA. V kept as 16KB sub-buffers with the proven
// R5 swizzle; K 64-row tiles reuse the row-swizzle (rows 32-63 alias 0-31).
// 8 waves / 256 q-rows / block, grid 8x8x4 = 256 blocks = 1/CU (R5-proven).
// ---------------------------------------------------------------------------
__global__ __launch_bounds__(512, 2) void flash_kernel(
    const short* __restrict__ Qb, const short* __restrict__ Kb,
    const short* __restrict__ Vt, const int* __restrict__ mask,
    float* __restrict__ Out, _Float16* __restrict__ Part,
    float* __restrict__ Lpart)
{
    __shared__ short Ks[2][KTILE * 256];   // 2 x 32 KB
    __shared__ short Vs[4][256 * 32];      // 4 x 16 KB

    const int tid  = threadIdx.x;
    const int wid  = tid >> 6;          // 0..7
    const int lane = tid & 63;
    const int l31  = lane & 31;
    const int hi   = lane >> 5;
    const int b  = blockIdx.x;
    const int q0 = blockIdx.y * 256;
    const int z  = blockIdx.z;

    const char* kgb = (const char*)(Kb + ((size_t)b * L_ + z * KRANGE) * D_);
    const char* vgb = (const char*)(Vt + (size_t)b * D_ * L_ + z * KRANGE);
    const int*  mg  = mask + b * L_ + z * KRANGE;

    // Q as MFMA B-operand: lane holds Q[q = l31][d = dt*16 + hi*8 + 0..7]
    bf16x8 qf[16];
    {
        const short* qrow = Qb + ((size_t)b * L_ + q0 + wid * 32 + l31) * D_ + hi * 8;
#pragma unroll
        for (int dt = 0; dt < 16; dt++)
            qf[dt] = *(const bf16x8*)(qrow + dt * 16);
    }

    // preload mask bits: bit t = mask[z*KRANGE + t*64 + lane] (lane = key-in-tile)
    uint32_t mbits = 0;
#pragma unroll
    for (int t = 0; t < NITER; t++)
        mbits |= (mg[t * KTILE + lane] != 0 ? 1u : 0u) << t;

    floatx16 o[8];
#pragma unroll
    for (int n = 0; n < 8; n++)
#pragma unroll
        for (int r = 0; r < 16; r++) o[n][r] = 0.f;
    float rsum = 0.f;

    // loop-invariant swizzled read bases (byte offsets):
    //   kf(dt): KBb ^ (dt<<5)   (half1 adds +16384 = rows 32..63)
    //   vf(n,kh): VBb ^ (n<<11 | kh<<5)  within a 16KB V sub-buffer
    const int KBb = l31 * 512 + ((((l31 & 7) ^ ((l31 >> 3) & 3)) ^ hi) << 4);
    const int VBb = l31 * 64 + (((((l31 >> 1) & 3) ^ ((l31 >> 3) & 1)) ^ hi) << 4);

    // loop-invariant staging offsets
    int koff[4], voff[2];
#pragma unroll
    for (int c = 0; c < 4; c++) {
        int row = wid * 8 + c * 2 + hi;                    // 8 rows/wave, 64 total
        int gk = l31 ^ (row & 7) ^ ((row >> 3) & 3);
        koff[c] = row * 512 + gk * 16;
    }
#pragma unroll
    for (int c = 0; c < 2; c++) {
        int d = (wid * 2 + c) * 16 + (lane >> 2);          // 16 d-rows/unit
        int gv = (lane & 3) ^ ((lane >> 3) & 3) ^ ((lane >> 5) & 1);
        voff[c] = d * (L_ * 2) + gv * 16;
    }

    // prologue: K(0)->Ks[0]; V(0)->Vs[2],Vs[3] (so the dummy PV at t=0
    // multiplies zero P-frags by finite data, never 0*garbage)
#pragma unroll
    for (int c = 0; c < 4; c++)
        async16(kgb + koff[c], &Ks[0][0] + (wid * 4 + c) * 512);
#pragma unroll
    for (int c = 0; c < 2; c++) {
        async16(vgb + voff[c],      &Vs[2][0] + (wid * 2 + c) * 512);
        async16(vgb + 64 + voff[c], &Vs[3][0] + (wid * 2 + c) * 512);
    }
    __builtin_amdgcn_s_waitcnt(0x0F70);  // vmcnt(0)
    __syncthreads();

    const float C2 = 0.09016844f;        // log2(e)/16
    bf16x8 pfA, pfB, pfC, pfD;           // P A-frags of prev tile (4 x 16 keys)
    {
        union { uint32_t u[4]; bf16x8 v; } zz;
        zz.u[0] = 0; zz.u[1] = 0; zz.u[2] = 0; zz.u[3] = 0;
        pfA = zz.v; pfB = zz.v; pfC = zz.v; pfD = zz.v;
    }

    // softmax of one 32-key half: s -> (pA, pB), accumulates rsum
    auto softmax32 = [&](const floatx16& s, uint32_t mb, bf16x8& pA, bf16x8& pB) {
        uint32_t w[8];
#pragma unroll
        for (int i = 0; i < 8; i++) {
            const int r0 = 2 * i, r1 = 2 * i + 1;
            const int k0 = (r0 & 3) + 8 * (r0 >> 2);
            float e0 = ((mb >> k0) & 1) ? exp2f(s[r0] * C2) : 0.f;
            float e1 = ((mb >> (k0 + 1)) & 1) ? exp2f(s[r1] * C2) : 0.f;
            rsum += e0 + e1;
            w[i] = cvtpk_bf16(e0, e1);
        }
        pl32swap(w[0], w[2]); pl32swap(w[1], w[3]);
        pl32swap(w[4], w[6]); pl32swap(w[5], w[7]);
        union { uint32_t u[4]; bf16x8 v; } ua, ub;
        ua.u[0] = w[0]; ua.u[1] = w[1]; ua.u[2] = w[2]; ua.u[3] = w[3];
        ub.u[0] = w[4]; ub.u[1] = w[5]; ub.u[2] = w[6]; ub.u[3] = w[7];
        pA = ua.v; pB = ub.v;
    };

    auto pvhalf = [&](const char* vl, bf16x8 pA, bf16x8 pB) {
#pragma unroll
        for (int n = 0; n < 8; n++) {
            bf16x8 vf0 = *(const bf16x8*)(vl + (VBb ^ (n << 11)));
            bf16x8 vf1 = *(const bf16x8*)(vl + (VBb ^ ((n << 11) | 32)));
            o[n] = __builtin_amdgcn_mfma_f32_32x32x16_bf16(pA, vf0, o[n], 0, 0, 0);
            o[n] = __builtin_amdgcn_mfma_f32_32x32x16_bf16(pB, vf1, o[n], 0, 0, 0);
        }
    };

    for (int t2 = 0; t2 < NITER; t2 += 2) {
#pragma unroll
        for (int half = 0; half < 2; half++) {
            const int t = t2 + half;
            const int buf = half;                    // == t & 1

            // stage K(t+1) -> Ks[buf^1] (t=7 clamps to K(0): L2-hot, never
            // read), V(t) -> Vs[buf*2], Vs[buf*2+1]
            {
                const char* kp = kgb + (size_t)((t + 1) & (NITER - 1)) * (KTILE * D_ * 2);
                const char* vp = vgb + (size_t)t * (KTILE * 2);
#pragma unroll
                for (int c = 0; c < 4; c++)
                    async16(kp + koff[c], &Ks[buf ^ 1][0] + (wid * 4 + c) * 512);
#pragma unroll
                for (int c = 0; c < 2; c++) {
                    async16(vp + voff[c],      &Vs[buf * 2][0]     + (wid * 2 + c) * 512);
                    async16(vp + 64 + voff[c], &Vs[buf * 2 + 1][0] + (wid * 2 + c) * 512);
                }
            }

            const char* kl  = (const char*)&Ks[buf][0];
            const char* vl0 = (const char*)&Vs[(buf ^ 1) * 2][0];
            const char* vl1 = (const char*)&Vs[(buf ^ 1) * 2 + 1][0];
            uint64_t bal = __ballot((mbits >> t) & 1);

            __builtin_amdgcn_s_setprio(1);

            // ---- QK half0 (keys 0..31 of tile t) ----
            floatx16 s;
#pragma unroll
            for (int r = 0; r < 16; r++) s[r] = 0.f;
#pragma unroll
            for (int dt = 0; dt < 16; dt++) {
                bf16x8 kf = *(const bf16x8*)(kl + (KBb ^ (dt << 5)));
                s = __builtin_amdgcn_mfma_f32_32x32x16_bf16(kf, qf[dt], s, 0, 0, 0);
            }

            // ---- PV_AB(t-1): independent MFMAs, interleave into QK chain ----
            pvhalf(vl0, pfA, pfB);

            // ---- sm0 -> pfA,pfB (keys 0..31) ----
            softmax32(s, (uint32_t)bal >> (hi * 4), pfA, pfB);

            // ---- QK half1 (keys 32..63) ----
#pragma unroll
            for (int r = 0; r < 16; r++) s[r] = 0.f;
#pragma unroll
            for (int dt = 0; dt < 16; dt++) {
                bf16x8 kf = *(const bf16x8*)(kl + 16384 + (KBb ^ (dt << 5)));
                s = __builtin_amdgcn_mfma_f32_32x32x16_bf16(kf, qf[dt], s, 0, 0, 0);
            }

            // ---- PV_CD(t-1) ----
            pvhalf(vl1, pfC, pfD);

            // ---- sm1 -> pfC,pfD (keys 32..63) ----
            softmax32(s, (uint32_t)(bal >> 32) >> (hi * 4), pfC, pfD);

            __builtin_amdgcn_s_setprio(0);

            __syncthreads();   // drains vmcnt (K(t+1),V(t) issued at iter top)
        }
    }

    // ---- final PV(NITER-1): V(7) is in Vs[2],Vs[3] ----
    __builtin_amdgcn_s_setprio(1);
    pvhalf((const char*)&Vs[2][0], pfA, pfB);
    pvhalf((const char*)&Vs[3][0], pfC, pfD);
    __builtin_amdgcn_s_setprio(0);

    // rsum: lane holds half the k-sum for q=l31; add partner half (lane^32)
    rsum += __shfl_xor(rsum, 32);

    const size_t BLD = (size_t)B_ * L_ * D_;
    const size_t rowbase = (size_t)b * L_ + q0 + wid * 32;
    // O layout: lane holds O[q = (r&3)+8*(r>>2)+4*hi][d = n*32 + l31]
    if (z == 0) {
        float* po = Out + rowbase * D_;
#pragma unroll
        for (int n = 0; n < 8; n++)
#pragma unroll
            for (int r = 0; r < 16; r++) {
                int q = (r & 3) + 8 * (r >> 2) + 4 * hi;
                po[(size_t)q * D_ + n * 32 + l31] = o[n][r];
            }
    } else {
        _Float16* pp = Part + (size_t)(z - 1) * BLD + rowbase * D_;
#pragma unroll
        for (int n = 0; n < 8; n++)
#pragma unroll
            for (int r = 0; r < 16; r++) {
                int q = (r & 3) + 8 * (r >> 2) + 4 * hi;
                pp[(size_t)q * D_ + n * 32 + l31] = (_Float16)o[n][r];
            }
    }
    if (lane < 32) {
        Lpart[(size_t)z * (B_ * L_) + rowbase + lane] = rsum;
    }
}

// ---------------------------------------------------------------------------
// Normalize: out = (P0_f32 + P1..3_f16) / (l0+l1+l2+l3)
// ---------------------------------------------------------------------------
__global__ __launch_bounds__(256) void norm_kernel(
    float* __restrict__ Out, const _Float16* __restrict__ Part,
    const float* __restrict__ Lpart)
{
    const int idx = blockIdx.x * 256 + threadIdx.x;
    const int row = idx >> 6;
    const int c   = (idx & 63) * 4;
    const size_t off = (size_t)row * D_ + c;
    const size_t BLD = (size_t)B_ * L_ * D_;
    float4 acc = *(float4*)(Out + off);
#pragma unroll
    for (int zz = 0; zz < 3; zz++) {
        half4_t h = *(const half4_t*)(Part + zz * BLD + off);
        acc.x += (float)h.x; acc.y += (float)h.y;
        acc.z += (float)h.z; acc.w += (float)h.w;
    }
    const int BL = B_ * L_;
    float l = Lpart[row] + Lpart[BL + row] + Lpart[2 * BL + row] + Lpart[3 * BL + row];
    float inv = 1.0f / l;
    acc.x *= inv; acc.y *= inv; acc.z *= inv; acc.w *= inv;
    *(float4*)(Out + off) = acc;
}

extern "C" void kernel_launch(void* const* d_in, const int* in_sizes, int n_in,
                              void* d_out, int out_size, void* d_ws, size_t ws_size,
                              hipStream_t stream) {
    const float* query = (const float*)d_in[0];
    const float* key   = (const float*)d_in[1];
    const float* value = (const float*)d_in[2];
    const int*   mask  = (const int*)d_in[3];
    const float* Wq_w  = (const float*)d_in[4];
    const float* Wq_b  = (const float*)d_in[5];
    const float* Wk_w  = (const float*)d_in[6];
    const float* Wk_b  = (const float*)d_in[7];
    float* out = (float*)d_out;

    const size_t BLD = (size_t)B_ * L_ * D_;
    short* qb = (short*)d_ws;
    short* kb = qb + BLD;
    short* vt = kb + BLD;
    _Float16* part = (_Float16*)(vt + BLD);
    float* lpart = (float*)(part + 3 * BLD);

    proj_kernel<<<dim3(256, 2), 256, 0, stream>>>(query, key, Wq_w, Wk_w, Wq_b, Wk_b, qb, kb);
    vtrans_kernel<<<dim3(64, 8), 256, 0, stream>>>(value, vt);
    flash_kernel<<<dim3(8, 8, 4), 512, 0, stream>>>(qb, kb, vt, mask, out, part, lpart);
    norm_kernel<<<dim3((B_ * L_ * D_ / 4) / 256), 256, 0, stream>>>(out, part, lpart);
}

// Round 9
// 167.849 us; speedup vs baseline: 1.0944x; 1.0944x over previous
//
#include <hip/hip_runtime.h>
#include <stdint.h>
#include <stddef.h>

#define B_ 8
#define L_ 2048
#define D_ 256
#define KRANGE 512
#define KTILE 32
#define NITER 16

typedef __bf16 bf16x8 __attribute__((ext_vector_type(8)));
typedef float floatx4 __attribute__((ext_vector_type(4)));
typedef float floatx16 __attribute__((ext_vector_type(16)));
typedef _Float16 half4_t __attribute__((ext_vector_type(4)));
typedef _Float16 half8_t __attribute__((ext_vector_type(8)));

__device__ __forceinline__ short f2bf(float f) {   // round-half-up (cheap)
    union { float f; uint32_t u; } v; v.f = f;
    return (short)((v.u + 0x8000u) >> 16);
}

__device__ __forceinline__ uint32_t pack2bf(float a, float b) {
    union { float f; uint32_t u; } x, y; x.f = a; y.f = b;
    return ((x.u + 0x8000u) >> 16) | ((y.u + 0x8000u) & 0xFFFF0000u);
}

__device__ __forceinline__ uint32_t cvtpk_bf16(float lo, float hi2) {
    uint32_t w;
    asm("v_cvt_pk_bf16_f32 %0, %1, %2" : "=v"(w) : "v"(lo), "v"(hi2));
    return w;
}

// swap(a[l+32], b[l]) for l<32: a's upper lanes <-> b's lower lanes
__device__ __forceinline__ void pl32swap(uint32_t &a, uint32_t &b) {
    asm("v_permlane32_swap_b32 %0, %1" : "+v"(a), "+v"(b));
}

__device__ __forceinline__ void async16(const void* g, void* l) {
    __builtin_amdgcn_global_load_lds(
        (__attribute__((address_space(1))) void*)g,
        (__attribute__((address_space(3))) void*)l,
        16, 0, 0);
}

// ---------------------------------------------------------------------------
// Fused q/k projection, double-buffered LDS: Out = bf16(X @ W^T + bias).
// ---------------------------------------------------------------------------
__global__ __launch_bounds__(256, 3) void proj_kernel(
    const float* __restrict__ Xq, const float* __restrict__ Xk,
    const float* __restrict__ Wq, const float* __restrict__ Wk,
    const float* __restrict__ bq, const float* __restrict__ bk,
    short* __restrict__ Oq, short* __restrict__ Ok)
{
    const float* X    = blockIdx.y ? Xk : Xq;
    const float* W    = blockIdx.y ? Wk : Wq;
    const float* bias = blockIdx.y ? bk : bq;
    short* Out        = blockIdx.y ? Ok : Oq;

    __shared__ uint32_t As[2][64 * 20];
    __shared__ uint32_t Ws[2][256 * 20];

    const int tid  = threadIdx.x;
    const int wid  = tid >> 6;
    const int lane = tid & 63;
    const int m16  = lane & 15;
    const int quad = lane >> 4;
    const int row0 = blockIdx.x * 64;
    const int ar = tid >> 2, cg = tid & 3;

    floatx4 acc[16];
    const floatx4 z4 = {0.f, 0.f, 0.f, 0.f};
#pragma unroll
    for (int i = 0; i < 16; i++) acc[i] = z4;

    // prologue: load + pack kc=0 into buf 0
    {
        const float* srcA = X + (size_t)(row0 + ar) * D_ + cg * 8;
        float4 a = *(const float4*)srcA, b2 = *(const float4*)(srcA + 4);
        uint4 u; u.x = pack2bf(a.x, a.y); u.y = pack2bf(a.z, a.w);
        u.z = pack2bf(b2.x, b2.y); u.w = pack2bf(b2.z, b2.w);
        *(uint4*)&As[0][ar * 20 + cg * 4] = u;
#pragma unroll
        for (int p = 0; p < 4; p++) {
            const float* srcW = W + (size_t)(p * 64 + ar) * D_ + cg * 8;
            float4 wa = *(const float4*)srcW, wb = *(const float4*)(srcW + 4);
            uint4 w; w.x = pack2bf(wa.x, wa.y); w.y = pack2bf(wa.z, wa.w);
            w.z = pack2bf(wb.x, wb.y); w.w = pack2bf(wb.z, wb.w);
            *(uint4*)&Ws[0][(p * 64 + ar) * 20 + cg * 4] = w;
        }
    }
    __syncthreads();

    for (int kc = 0; kc < 8; kc++) {
        const int buf = kc & 1;
        // issue global loads for kc+1
        float4 na, nb, nwa[4], nwb[4];
        if (kc < 7) {
            const int k1 = (kc + 1) * 32;
            const float* srcA = X + (size_t)(row0 + ar) * D_ + k1 + cg * 8;
            na = *(const float4*)srcA; nb = *(const float4*)(srcA + 4);
#pragma unroll
            for (int p = 0; p < 4; p++) {
                const float* srcW = W + (size_t)(p * 64 + ar) * D_ + k1 + cg * 8;
                nwa[p] = *(const float4*)srcW; nwb[p] = *(const float4*)(srcW + 4);
            }
        }
        // MFMA on current buffer
        bf16x8 af = *(const bf16x8*)&As[buf][(wid * 16 + m16) * 20 + quad * 4];
#pragma unroll
        for (int n = 0; n < 16; n++) {
            bf16x8 bfr = *(const bf16x8*)&Ws[buf][(n * 16 + m16) * 20 + quad * 4];
            acc[n] = __builtin_amdgcn_mfma_f32_16x16x32_bf16(af, bfr, acc[n], 0, 0, 0);
        }
        // pack + write next buffer
        if (kc < 7) {
            uint4 u; u.x = pack2bf(na.x, na.y); u.y = pack2bf(na.z, na.w);
            u.z = pack2bf(nb.x, nb.y); u.w = pack2bf(nb.z, nb.w);
            *(uint4*)&As[buf ^ 1][ar * 20 + cg * 4] = u;
#pragma unroll
            for (int p = 0; p < 4; p++) {
                uint4 w; w.x = pack2bf(nwa[p].x, nwa[p].y); w.y = pack2bf(nwa[p].z, nwa[p].w);
                w.z = pack2bf(nwb[p].x, nwb[p].y); w.w = pack2bf(nwb[p].z, nwb[p].w);
                *(uint4*)&Ws[buf ^ 1][(p * 64 + ar) * 20 + cg * 4] = w;
            }
        }
        __syncthreads();
    }
#pragma unroll
    for (int n = 0; n < 16; n++) {
        const int col = n * 16 + m16;
        const float bv = bias[col];
#pragma unroll
        for (int r = 0; r < 4; r++) {
            const int row = row0 + wid * 16 + quad * 4 + r;
            Out[(size_t)row * D_ + col] = f2bf(acc[n][r] + bv);
        }
    }
}

// ---------------------------------------------------------------------------
// V transpose: Vt[b][d][l] = bf16(V[b][l][d]).
// ---------------------------------------------------------------------------
__global__ __launch_bounds__(256, 2) void vtrans_kernel(
    const float* __restrict__ V, short* __restrict__ Vt)
{
    __shared__ uint32_t T[256 * 20];
    const int tid = threadIdx.x;
    const int b  = blockIdx.y;
    const int l0 = blockIdx.x * 32;
    const int r2 = tid >> 4;
    const int dg = tid & 15;
    const int lp = r2 ^ ((dg & 3) << 2);
#pragma unroll
    for (int p = 0; p < 4; p++) {
        int d0 = (dg + p * 16) * 4;
        const float* src = V + ((size_t)b * L_ + l0 + r2 * 2) * D_ + d0;
        float4 e0 = *(const float4*)src;
        float4 e1 = *(const float4*)(src + D_);
        T[(d0 + 0) * 20 + lp] = pack2bf(e0.x, e1.x);
        T[(d0 + 1) * 20 + lp] = pack2bf(e0.y, e1.y);
        T[(d0 + 2) * 20 + lp] = pack2bf(e0.z, e1.z);
        T[(d0 + 3) * 20 + lp] = pack2bf(e0.w, e1.w);
    }
    __syncthreads();
#pragma unroll
    for (int p = 0; p < 4; p++) {
        int d = (tid >> 2) + p * 64;
        int c = tid & 3;
        int cp = c ^ ((d >> 2) & 3);
        uint4 u = *(const uint4*)&T[d * 20 + cp * 4];
        *(uint4*)(Vt + ((size_t)b * D_ + d) * L_ + l0 + c * 8) = u;
    }
}

// ---------------------------------------------------------------------------
// Flash attention, static softmax, ksplit=4, 32x32x16 MFMA, swapped QK^T,
// in-register P via cvt_pk + permlane32_swap. R5 core + T3/T4 pipeline:
// 3-deep K/V LDS buffers, raw s_barrier, counted vmcnt(4) so the newest
// prefetch batch (K(t+2),V(t+1)) stays in flight across the barrier.
// NOTE: async16 LDS dest spans are 1024 B per unit (64 lanes x 16 B) —
// R7/R8's *512 on char* halved them (R8 NaN post-mortem).
// 8 waves / 256 q-rows / block, grid 8x8x4 = 256 blocks = 1/CU.
// ---------------------------------------------------------------------------
__global__ __launch_bounds__(512, 2) void flash_kernel(
    const short* __restrict__ Qb, const short* __restrict__ Kb,
    const short* __restrict__ Vt, const int* __restrict__ mask,
    float* __restrict__ Out, _Float16* __restrict__ Part,
    float* __restrict__ Lpart)
{
    __shared__ short Ks[3][KTILE * 256];   // 3 x 16 KB
    __shared__ short Vs[3][256 * KTILE];   // 3 x 16 KB

    const int tid  = threadIdx.x;
    const int wid  = tid >> 6;          // 0..7
    const int lane = tid & 63;
    const int l31  = lane & 31;
    const int hi   = lane >> 5;
    const int b  = blockIdx.x;
    const int yb = blockIdx.y;
    const int q0 = yb * 256;
    const int z  = blockIdx.z;

    const char* kgb = (const char*)(Kb + ((size_t)b * L_ + z * KRANGE) * D_);
    const char* vgb = (const char*)(Vt + (size_t)b * D_ * L_ + z * KRANGE);
    const int*  mg  = mask + b * L_ + z * KRANGE;

    // Q as MFMA B-operand: lane holds Q[q = l31][d = dt*16 + hi*8 + 0..7]
    bf16x8 qf[16];
    {
        const short* qrow = Qb + ((size_t)b * L_ + q0 + wid * 32 + l31) * D_ + hi * 8;
#pragma unroll
        for (int dt = 0; dt < 16; dt++)
            qf[dt] = *(const bf16x8*)(qrow + dt * 16);
    }

    // preload mask bits: bit t = mask[z*KRANGE + t*32 + l31]
    uint32_t mbits = 0;
#pragma unroll
    for (int t = 0; t < NITER; t++)
        mbits |= (mg[t * KTILE + l31] != 0 ? 1u : 0u) << t;

    floatx16 o[8];
#pragma unroll
    for (int n = 0; n < 8; n++)
#pragma unroll
        for (int r = 0; r < 16; r++) o[n][r] = 0.f;
    float rsum = 0.f;

    // loop-invariant swizzled read bases (byte offsets):
    //   kf(dt): KBb ^ (dt<<5)
    //   vf(n,kh): VBb ^ (n<<11 | kh<<5)
    const int KBb = l31 * 512 + ((((l31 & 7) ^ ((l31 >> 3) & 3)) ^ hi) << 4);
    const int VBb = l31 * 64 + (((((l31 >> 1) & 3) ^ ((l31 >> 3) & 1)) ^ hi) << 4);

    // loop-invariant staging offsets; 8 waves x 2 units each for K and V
    int koff[2], voff[2];
#pragma unroll
    for (int c = 0; c < 2; c++) {
        int row = wid * 4 + c * 2 + hi;                    // 2 rows/unit
        int gk = l31 ^ (row & 7) ^ ((row >> 3) & 3);
        koff[c] = row * 512 + gk * 16;
        int d = (wid * 2 + c) * 16 + (lane >> 2);          // 16 d-rows/unit
        int gv = (lane & 3) ^ ((lane >> 3) & 3) ^ ((lane >> 5) & 1);
        voff[c] = d * (L_ * 2) + gv * 16;
    }

    // prologue: K(0)->Ks[0], K(1)->Ks[1]; V(0)->Vs[2] (dummy target of the
    // t=0 zero-P PV: 0*finite, never 0*garbage) and V(0)->Vs[0].
#pragma unroll
    for (int c = 0; c < 2; c++) {
        async16(kgb + koff[c], (char*)&Ks[0][0] + (wid * 2 + c) * 1024);
        async16(vgb + voff[c], (char*)&Vs[2][0] + (wid * 2 + c) * 1024);
        async16(kgb + (KTILE * D_ * 2) + koff[c], (char*)&Ks[1][0] + (wid * 2 + c) * 1024);
        async16(vgb + voff[c], (char*)&Vs[0][0] + (wid * 2 + c) * 1024);
    }
    __builtin_amdgcn_s_waitcnt(0x0F70);  // vmcnt(0) once, in prologue
    __syncthreads();

    const float C2 = 0.09016844f;        // log2(e)/16
    bf16x8 pfA, pfB;                     // P A-frags (k 0..15, 16..31) of prev iter
    {
        union { uint32_t u[4]; bf16x8 v; } zz;
        zz.u[0] = 0; zz.u[1] = 0; zz.u[2] = 0; zz.u[3] = 0;
        pfA = zz.v; pfB = zz.v;
    }

    // rotating buffer pointers: kCur=K(t), kNxt=K(t+1), kDst<-K(t+2);
    // vP=V(t-1) (PV source), vQ=V(t), vR<-V(t+1)
    short* kCur = &Ks[0][0]; short* kNxt = &Ks[1][0]; short* kDst = &Ks[2][0];
    short* vP   = &Vs[2][0]; short* vQ   = &Vs[0][0]; short* vR   = &Vs[1][0];

    for (int t = 0; t < NITER; t++) {
        // stage K(t+2) -> kDst, V(t+1) -> vR (indices clamped mod 16; the
        // wrapped tiles are L2-hot dummies never read)
        {
            const char* kp = kgb + (size_t)((t + 2) & 15) * (KTILE * D_ * 2);
            const char* vp = vgb + (size_t)((t + 1) & 15) * (KTILE * 2);
#pragma unroll
            for (int c = 0; c < 2; c++) {
                async16(kp + koff[c], (char*)kDst + (wid * 2 + c) * 1024);
                async16(vp + voff[c], (char*)vR + (wid * 2 + c) * 1024);
            }
        }

        // ---- QK(t), swapped: S^T[k][q] = mfma(K, Q); two chains ----
        const char* kl = (const char*)kCur;
        floatx16 s0, s1;
#pragma unroll
        for (int r = 0; r < 16; r++) { s0[r] = 0.f; s1[r] = 0.f; }
        __builtin_amdgcn_s_setprio(1);
#pragma unroll
        for (int dt = 0; dt < 16; dt += 2) {
            bf16x8 kf0 = *(const bf16x8*)(kl + (KBb ^ (dt << 5)));
            bf16x8 kf1 = *(const bf16x8*)(kl + (KBb ^ ((dt + 1) << 5)));
            s0 = __builtin_amdgcn_mfma_f32_32x32x16_bf16(kf0, qf[dt], s0, 0, 0, 0);
            s1 = __builtin_amdgcn_mfma_f32_32x32x16_bf16(kf1, qf[dt + 1], s1, 0, 0, 0);
        }

        // ---- PV(t-1) from register P-fragments (unconditional) ----
        const char* vl = (const char*)vP;
#pragma unroll
        for (int n = 0; n < 8; n++) {
            bf16x8 vf0 = *(const bf16x8*)(vl + (VBb ^ (n << 11)));
            bf16x8 vf1 = *(const bf16x8*)(vl + (VBb ^ ((n << 11) | 32)));
            o[n] = __builtin_amdgcn_mfma_f32_32x32x16_bf16(pfA, vf0, o[n], 0, 0, 0);
            o[n] = __builtin_amdgcn_mfma_f32_32x32x16_bf16(pfB, vf1, o[n], 0, 0, 0);
        }
        __builtin_amdgcn_s_setprio(0);

        // ---- softmax(t): P = exp2(S*C2) masked, packed to bf16 A-frags ----
        // lane (q=l31, hi) holds S^T at k = (r&3) + 8*(r>>2) + 4*hi
        uint32_t mb = (uint32_t)__ballot((mbits >> t) & 1) >> (hi * 4);
        uint32_t w[8];
#pragma unroll
        for (int i = 0; i < 8; i++) {
            const int r0 = 2 * i, r1 = 2 * i + 1;
            const int k0 = (r0 & 3) + 8 * (r0 >> 2);
            float sv0 = s0[r0] + s1[r0];
            float sv1 = s0[r1] + s1[r1];
            float e0 = ((mb >> k0) & 1) ? exp2f(sv0 * C2) : 0.f;
            float e1 = ((mb >> (k0 + 1)) & 1) ? exp2f(sv1 * C2) : 0.f;
            rsum += e0 + e1;
            w[i] = cvtpk_bf16(e0, e1);
        }
        pl32swap(w[0], w[2]); pl32swap(w[1], w[3]);
        pl32swap(w[4], w[6]); pl32swap(w[5], w[7]);
        {
            union { uint32_t u[4]; bf16x8 v; } ua, ub;
            ua.u[0] = w[0]; ua.u[1] = w[1]; ua.u[2] = w[2]; ua.u[3] = w[3];
            ub.u[0] = w[4]; ub.u[1] = w[5]; ub.u[2] = w[6]; ub.u[3] = w[7];
            pfA = ua.v; pfB = ub.v;
        }

        // counted drain: retire K(t+1),V(t) (oldest 4); keep the newest 4
        // (K(t+2),V(t+1)) in flight across the barrier.
        asm volatile("s_waitcnt vmcnt(4)" ::: "memory");
        __builtin_amdgcn_s_barrier();
        asm volatile("" ::: "memory");

        // rotate buffers
        short* tk = kCur; kCur = kNxt; kNxt = kDst; kDst = tk;
        short* tv = vP;   vP = vQ;     vQ = vR;     vR = tv;
    }

    // ---- final PV(NITER-1): vP now holds V(15) ----
    {
        const char* vl = (const char*)vP;
        __builtin_amdgcn_s_setprio(1);
#pragma unroll
        for (int n = 0; n < 8; n++) {
            bf16x8 vf0 = *(const bf16x8*)(vl + (VBb ^ (n << 11)));
            bf16x8 vf1 = *(const bf16x8*)(vl + (VBb ^ ((n << 11) | 32)));
            o[n] = __builtin_amdgcn_mfma_f32_32x32x16_bf16(pfA, vf0, o[n], 0, 0, 0);
            o[n] = __builtin_amdgcn_mfma_f32_32x32x16_bf16(pfB, vf1, o[n], 0, 0, 0);
        }
        __builtin_amdgcn_s_setprio(0);
    }

    // rsum: lane holds half the k-sum for q=l31; add partner half (lane^32)
    rsum += __shfl_xor(rsum, 32);

    const size_t BLD = (size_t)B_ * L_ * D_;
    const size_t rowbase = (size_t)b * L_ + q0 + wid * 32;
    // O layout: lane holds O[q = (r&3)+8*(r>>2)+4*hi][d = n*32 + l31]
    if (z == 0) {
        float* po = Out + rowbase * D_;
#pragma unroll
        for (int n = 0; n < 8; n++)
#pragma unroll
            for (int r = 0; r < 16; r++) {
                int q = (r & 3) + 8 * (r >> 2) + 4 * hi;
                po[(size_t)q * D_ + n * 32 + l31] = o[n][r];
            }
    } else {
        // full-line chunked layout: chunk idx = ((((b*8+y)*8+w)*8+n)*2+h2)*64+lane,
        // 8 f16 (r = h2*8 .. h2*8+7) per chunk. 64 lanes x 16B = 1KB contiguous.
        _Float16* pp = Part + (size_t)(z - 1) * BLD;
#pragma unroll
        for (int n = 0; n < 8; n++)
#pragma unroll
            for (int h2 = 0; h2 < 2; h2++) {
                half8_t hv;
#pragma unroll
                for (int i = 0; i < 8; i++) hv[i] = (_Float16)o[n][h2 * 8 + i];
                size_t cidx = ((((size_t)((b * 8 + yb) * 8 + wid)) * 8 + n) * 2 + h2) * 64 + lane;
                *(half8_t*)(pp + cidx * 8) = hv;
            }
    }
    if (lane < 32) {
        Lpart[(size_t)z * (B_ * L_) + rowbase + lane] = rsum;
    }
}

// ---------------------------------------------------------------------------
// Normalize: out = (Out_f32 + sum of 3 Part_f16 slices) / (l0+l1+l2+l3).
// Part is in the chunked layout written by flash; gid == chunk index.
// One thread per 8-element chunk: grid = BLD/8/256 = 2048 blocks.
// ---------------------------------------------------------------------------
__global__ __launch_bounds__(256) void norm_kernel(
    float* __restrict__ Out, const _Float16* __restrict__ Part,
    const float* __restrict__ Lpart)
{
    const int gid  = blockIdx.x * 256 + threadIdx.x;   // 0 .. 524287
    const int lane = gid & 63;
    const int h2   = (gid >> 6) & 1;
    const int n    = (gid >> 7) & 7;
    const int w    = (gid >> 10) & 7;
    const int yb   = (gid >> 13) & 7;
    const int b    = gid >> 16;
    const int l31  = lane & 31, hi = lane >> 5;
    const int d    = n * 32 + l31;
    const int rowbase = b * L_ + yb * 256 + w * 32;
    const size_t BLD = (size_t)B_ * L_ * D_;
    const int BL = B_ * L_;

    float acc[8];
#pragma unroll
    for (int i = 0; i < 8; i++) acc[i] = 0.f;
#pragma unroll
    for (int zz = 0; zz < 3; zz++) {
        half8_t hv = *(const half8_t*)(Part + zz * BLD + (size_t)gid * 8);
#pragma unroll
        for (int i = 0; i < 8; i++) acc[i] += (float)hv[i];
    }
#pragma unroll
    for (int i = 0; i < 8; i++) {
        const int r = h2 * 8 + i;
        const int q = (r & 3) + 8 * (r >> 2) + 4 * hi;
        const int row = rowbase + q;
        float l = Lpart[row] + Lpart[BL + row] + Lpart[2 * BL + row] + Lpart[3 * BL + row];
        const size_t off = (size_t)row * D_ + d;
        Out[off] = (Out[off] + acc[i]) / l;
    }
}

extern "C" void kernel_launch(void* const* d_in, const int* in_sizes, int n_in,
                              void* d_out, int out_size, void* d_ws, size_t ws_size,
                              hipStream_t stream) {
    const float* query = (const float*)d_in[0];
    const float* key   = (const float*)d_in[1];
    const float* value = (const float*)d_in[2];
    const int*   mask  = (const int*)d_in[3];
    const float* Wq_w  = (const float*)d_in[4];
    const float* Wq_b  = (const float*)d_in[5];
    const float* Wk_w  = (const float*)d_in[6];
    const float* Wk_b  = (const float*)d_in[7];
    float* out = (float*)d_out;

    const size_t BLD = (size_t)B_ * L_ * D_;
    short* qb = (short*)d_ws;
    short* kb = qb + BLD;
    short* vt = kb + BLD;
    _Float16* part = (_Float16*)(vt + BLD);
    float* lpart = (float*)(part + 3 * BLD);

    proj_kernel<<<dim3(256, 2), 256, 0, stream>>>(query, key, Wq_w, Wk_w, Wq_b, Wk_b, qb, kb);
    vtrans_kernel<<<dim3(64, 8), 256, 0, stream>>>(value, vt);
    flash_kernel<<<dim3(8, 8, 4), 512, 0, stream>>>(qb, kb, vt, mask, out, part, lpart);
    norm_kernel<<<dim3((B_ * L_ * D_ / 8) / 256), 256, 0, stream>>>(out, part, lpart);
}